// Round 8
// baseline (316.206 us; speedup 1.0000x reference)
//
#include <hip/hip_runtime.h>
#include <math.h>

#define HD 4096
#define LD 2048

typedef float f32x4 __attribute__((ext_vector_type(4)));

// ---------------- reduction helpers ----------------
__device__ __forceinline__ float wave_sum(float v) {
#pragma unroll
    for (int off = 32; off > 0; off >>= 1) v += __shfl_down(v, off, 64);
    return v;
}
__device__ __forceinline__ float wave_max(float v) {
#pragma unroll
    for (int off = 32; off > 0; off >>= 1) v = fmaxf(v, __shfl_down(v, off, 64));
    return v;
}
__device__ __forceinline__ float block_sum256(float v, float* sm) {
    v = wave_sum(v);
    if ((threadIdx.x & 63) == 0) sm[threadIdx.x >> 6] = v;
    __syncthreads();
    float r = sm[0] + sm[1] + sm[2] + sm[3];
    __syncthreads();
    return r;
}
__device__ __forceinline__ float block_max256(float v, float* sm) {
    v = wave_max(v);
    if ((threadIdx.x & 63) == 0) sm[threadIdx.x >> 6] = v;
    __syncthreads();
    float r = fmaxf(fmaxf(sm[0], sm[1]), fmaxf(sm[2], sm[3]));
    __syncthreads();
    return r;
}

// ---------------- per-thread partial dots (256-thread blocks) ----------------
// W rows are read-once: non-temporal (no L2 allocate). X vectors stay cached.
__device__ __forceinline__ float pdot4096(const f32x4* __restrict__ W4,
                                          const float4* __restrict__ X4, int t) {
    float a0 = 0.f, a1 = 0.f;
#pragma unroll
    for (int i = 0; i < 4; i += 2) {
        int idx = i * 256 + t;
        f32x4 w = __builtin_nontemporal_load(W4 + idx);
        float4 x = X4[idx];
        a0 = fmaf(w[0], x.x, a0); a0 = fmaf(w[1], x.y, a0);
        a0 = fmaf(w[2], x.z, a0); a0 = fmaf(w[3], x.w, a0);
        int idx2 = idx + 256;
        f32x4 w2 = __builtin_nontemporal_load(W4 + idx2);
        float4 x2 = X4[idx2];
        a1 = fmaf(w2[0], x2.x, a1); a1 = fmaf(w2[1], x2.y, a1);
        a1 = fmaf(w2[2], x2.z, a1); a1 = fmaf(w2[3], x2.w, a1);
    }
    return a0 + a1;
}
__device__ __forceinline__ float pdot8192(const f32x4* __restrict__ W4,
                                          const float4* __restrict__ X1,
                                          const float4* __restrict__ X2, int t) {
    float a0 = 0.f, a1 = 0.f;
#pragma unroll
    for (int i = 0; i < 4; ++i) {
        int idx = i * 256 + t;
        f32x4 w = __builtin_nontemporal_load(W4 + idx);
        float4 x = X1[idx];
        a0 = fmaf(w[0], x.x, a0); a0 = fmaf(w[1], x.y, a0);
        a0 = fmaf(w[2], x.z, a0); a0 = fmaf(w[3], x.w, a0);
        int idx2 = idx + 1024;
        f32x4 w2 = __builtin_nontemporal_load(W4 + idx2);
        float4 x2 = X2[idx];
        a1 = fmaf(w2[0], x2.x, a1); a1 = fmaf(w2[1], x2.y, a1);
        a1 = fmaf(w2[2], x2.z, a1); a1 = fmaf(w2[3], x2.w, a1);
    }
    return a0 + a1;
}

// hh filler row: ghh[r] = W_hh[r]·h + b_ih[r] + b_hh[r]
__device__ __forceinline__ void hh_row(
    int r, const float* __restrict__ Whh, const float* __restrict__ bih,
    const float* __restrict__ bhh, const float* __restrict__ h,
    float* __restrict__ ghh)
{
    const int t = threadIdx.x;
    float v = pdot4096(reinterpret_cast<const f32x4*>(Whh + (size_t)r * HD),
                       reinterpret_cast<const float4*>(h), t);
    __shared__ float smr[4];
    float acc = wave_sum(v);
    if ((t & 63) == 0) smr[t >> 6] = acc;
    __syncthreads();
    if (t == 0) ghh[r] = smr[0] + smr[1] + smr[2] + smr[3] + bih[r] + bhh[r];
}

// ---------------- K1: attn logits (2048) + hh rows [0,4096); zeroes K5's counter --------
__global__ __launch_bounds__(256) void k1_attn_hh(
    const float* __restrict__ Wattn, const float* __restrict__ battn,
    const float* __restrict__ emb, const int* __restrict__ token,
    const float* __restrict__ h,
    const float* __restrict__ Whh, const float* __restrict__ bih,
    const float* __restrict__ bhh,
    float* __restrict__ attn_logits, float* __restrict__ ghh,
    unsigned int* __restrict__ cnt5)
{
    const int bx = blockIdx.x;
    const int t = threadIdx.x;
    if (bx == 0 && t == 0) *cnt5 = 0u;   // ordered before K5 by kernel boundary
    if (bx < LD) {
        const float* x1 = emb + (size_t)token[0] * HD;
        float v = pdot8192(reinterpret_cast<const f32x4*>(Wattn + (size_t)bx * 8192),
                           reinterpret_cast<const float4*>(x1),
                           reinterpret_cast<const float4*>(h), t);
        __shared__ float sm[4];
        float acc = wave_sum(v);
        if ((t & 63) == 0) sm[t >> 6] = acc;
        __syncthreads();
        if (t == 0) attn_logits[bx] = sm[0] + sm[1] + sm[2] + sm[3] + battn[bx];
    } else {
        hh_row(bx - LD, Whh, bih, bhh, h, ghh);
    }
}

// ---------------- K2: softmax+ctx (64 col-blocks) + attn_w writer + hh [4096,10240) ------
__global__ __launch_bounds__(256) void k2_ctx_hh(
    const float* __restrict__ logits, const float* __restrict__ enc,
    const float* __restrict__ Whh, const float* __restrict__ bih,
    const float* __restrict__ bhh, const float* __restrict__ h,
    float* __restrict__ ctx, float* __restrict__ attn_out, float* __restrict__ ghh)
{
    const int bx = blockIdx.x;
    const int t = threadIdx.x;
    if (bx <= 64) {
        // redundant softmax per block (2048 logits from L2)
        __shared__ float sm[4];
        float vals[8];
        float m = -INFINITY;
#pragma unroll
        for (int i = 0; i < 8; ++i) { vals[i] = logits[i * 256 + t]; m = fmaxf(m, vals[i]); }
        m = block_max256(m, sm);
        float s = 0.f;
#pragma unroll
        for (int i = 0; i < 8; ++i) { vals[i] = expf(vals[i] - m); s += vals[i]; }
        s = block_sum256(s, sm);
        const float inv = 1.f / s;
        if (bx == 64) {
#pragma unroll
            for (int i = 0; i < 8; ++i) attn_out[i * 256 + t] = vals[i] * inv;
            return;
        }
        __shared__ float smw[2048];
#pragma unroll
        for (int i = 0; i < 8; ++i) smw[i * 256 + t] = vals[i] * inv;
        __syncthreads();
        // block bx covers 64 cols (16 float4): thread rg = t>>4 (128 rows each), cc = t&15
        const int rg = t >> 4;
        const int cc = t & 15;
        const int col4 = bx * 16 + cc;
        const float4* E = reinterpret_cast<const float4*>(enc);
        float4 acc = make_float4(0.f, 0.f, 0.f, 0.f);
        const int k0 = rg * 128;
#pragma unroll 8
        for (int k = k0; k < k0 + 128; ++k) {
            float wv = smw[k];
            float4 ev = E[(size_t)k * 1024 + col4];
            acc.x = fmaf(wv, ev.x, acc.x); acc.y = fmaf(wv, ev.y, acc.y);
            acc.z = fmaf(wv, ev.z, acc.z); acc.w = fmaf(wv, ev.w, acc.w);
        }
        __shared__ float4 red[16][16];
        red[rg][cc] = acc;
        __syncthreads();
        if (t < 16) {
            float4 s2 = red[0][t];
#pragma unroll
            for (int k = 1; k < 16; ++k) {
                float4 v = red[k][t];
                s2.x += v.x; s2.y += v.y; s2.z += v.z; s2.w += v.w;
            }
            reinterpret_cast<float4*>(ctx)[bx * 16 + t] = s2;
        }
    } else {
        hh_row(4096 + (bx - 65), Whh, bih, bhh, h, ghh);
    }
}

// ---------------- K3: comb (4096 rows) + hh rows [10240,16384) ----------------
__global__ __launch_bounds__(256) void k3_comb_hh(
    const float* __restrict__ W, const float* __restrict__ bias,
    const float* __restrict__ emb, const int* __restrict__ token,
    const float* __restrict__ ctx,
    const float* __restrict__ Whh, const float* __restrict__ bih,
    const float* __restrict__ bhh, const float* __restrict__ h,
    float* __restrict__ xvec, float* __restrict__ ghh)
{
    const int bx = blockIdx.x;
    const int t = threadIdx.x;
    if (bx < HD) {
        const float* x1 = emb + (size_t)token[0] * HD;
        float v = pdot8192(reinterpret_cast<const f32x4*>(W + (size_t)bx * 8192),
                           reinterpret_cast<const float4*>(x1),
                           reinterpret_cast<const float4*>(ctx), t);
        __shared__ float sm[4];
        float acc = wave_sum(v);
        if ((t & 63) == 0) sm[t >> 6] = acc;
        __syncthreads();
        if (t == 0) xvec[bx] = fmaxf(sm[0] + sm[1] + sm[2] + sm[3] + bias[bx], 0.f);
    } else {
        hh_row(10240 + (bx - HD), Whh, bih, bhh, h, ghh);
    }
}

// ---------------- K4: gates_ih (4 rows per block) + LSTM cell fused ----------------
__global__ __launch_bounds__(256) void k4_ih_cell(
    const float* __restrict__ Wih, const float* __restrict__ ghh,
    const float* __restrict__ x, const float* __restrict__ c,
    float* __restrict__ out)
{
    const int j = blockIdx.x;
    const int t = threadIdx.x;
    const float4* X = reinterpret_cast<const float4*>(x);
    float acc[4];
#pragma unroll
    for (int g = 0; g < 4; ++g)
        acc[g] = pdot4096(reinterpret_cast<const f32x4*>(Wih + (size_t)(g * HD + j) * HD), X, t);
    __shared__ float sm[4][4];
#pragma unroll
    for (int g = 0; g < 4; ++g) {
        float v = wave_sum(acc[g]);
        if ((t & 63) == 0) sm[t >> 6][g] = v;
    }
    __syncthreads();
    if (t == 0) {
        float gi = sm[0][0] + sm[1][0] + sm[2][0] + sm[3][0] + ghh[j];
        float gf = sm[0][1] + sm[1][1] + sm[2][1] + sm[3][1] + ghh[HD + j];
        float gg = sm[0][2] + sm[1][2] + sm[2][2] + sm[3][2] + ghh[2 * HD + j];
        float go = sm[0][3] + sm[1][3] + sm[2][3] + sm[3][3] + ghh[3 * HD + j];
        float si = 1.f / (1.f + expf(-gi));
        float sf = 1.f / (1.f + expf(-gf));
        float so = 1.f / (1.f + expf(-go));
        float cn = sf * c[j] + si * tanhf(gg);
        float hn = so * tanhf(cn);
        out[HD + j] = hn;       // h_new
        out[2 * HD + j] = cn;   // c_new
    }
}

// ---------------- K5: logits GEMV + last-block log_softmax (threadfence-counter) --------
__global__ __launch_bounds__(256) void k5_out_lsm(
    const float* __restrict__ W, const float* __restrict__ bias,
    const float* __restrict__ x, float* __restrict__ logits,
    float* __restrict__ out, unsigned int* __restrict__ cnt)
{
    const int row = blockIdx.x;
    const int t = threadIdx.x;
    float v = pdot4096(reinterpret_cast<const f32x4*>(W + (size_t)row * HD),
                       reinterpret_cast<const float4*>(x), t);
    __shared__ float sm[4];
    float acc = wave_sum(v);
    if ((t & 63) == 0) sm[t >> 6] = acc;
    __syncthreads();
    if (t == 0) logits[row] = sm[0] + sm[1] + sm[2] + sm[3] + bias[row];

    // deterministic last-block continuation (no spin, no co-residency assumption)
    __shared__ unsigned int lastFlag;
    if (t == 0) {
        __threadfence();                       // release: publish logits[row]
        unsigned int old = atomicAdd(cnt, 1u); // device-scope
        lastFlag = (old == (unsigned int)(gridDim.x - 1)) ? 1u : 0u;
    }
    __syncthreads();
    if (lastFlag) {
        __threadfence();                       // acquire: see all blocks' logits
        float vals[16];
        float m = -INFINITY;
#pragma unroll
        for (int i = 0; i < 16; ++i) { vals[i] = logits[i * 256 + t]; m = fmaxf(m, vals[i]); }
        m = block_max256(m, sm);
        float s = 0.f;
#pragma unroll
        for (int i = 0; i < 16; ++i) s += expf(vals[i] - m);
        s = block_sum256(s, sm);
        float lse = m + logf(s);
#pragma unroll
        for (int i = 0; i < 16; ++i) out[i * 256 + t] = vals[i] - lse;
    }
}

extern "C" void kernel_launch(void* const* d_in, const int* in_sizes, int n_in,
                              void* d_out, int out_size, void* d_ws, size_t ws_size,
                              hipStream_t stream)
{
    const int*   token  = (const int*)  d_in[0];
    const float* h      = (const float*)d_in[1];
    const float* c      = (const float*)d_in[2];
    const float* enc    = (const float*)d_in[3];
    const float* emb    = (const float*)d_in[4];
    const float* W_attn = (const float*)d_in[5];
    const float* b_attn = (const float*)d_in[6];
    const float* W_comb = (const float*)d_in[7];
    const float* b_comb = (const float*)d_in[8];
    const float* W_ih   = (const float*)d_in[9];
    const float* W_hh   = (const float*)d_in[10];
    const float* b_ih   = (const float*)d_in[11];
    const float* b_hh   = (const float*)d_in[12];
    const float* W_out  = (const float*)d_in[13];
    const float* b_out  = (const float*)d_in[14];
    float* out = (float*)d_out;  // [logp 4096 | h_new 4096 | c_new 4096 | attn_w 2048]

    // ws layout (floats)
    float* ws          = (float*)d_ws;
    float* attn_logits = ws;               // 2048
    float* ghh         = ws + 2048;        // 16384
    float* ctx         = ws + 18432;       // 4096
    float* xvec        = ws + 22528;       // 4096
    float* logits      = ws + 26624;       // 4096
    unsigned int* cnt5 = (unsigned int*)(ws + 30720);

    // K1: attn logits (64 MB) + hh rows 0..4095 (64 MB); zero K5 counter
    k1_attn_hh<<<LD + 4096, 256, 0, stream>>>(
        W_attn, b_attn, emb, token, h, W_hh, b_ih, b_hh, attn_logits, ghh, cnt5);
    // K2: softmax + coalesced ctx (32 MB) + attn_w writer + hh rows 4096..10239 (96 MB)
    k2_ctx_hh<<<65 + 6144, 256, 0, stream>>>(
        attn_logits, enc, W_hh, b_ih, b_hh, h, ctx, out + 3 * HD, ghh);
    // K3: comb (128 MB) + hh rows 10240..16383 (96 MB)
    k3_comb_hh<<<HD + 6144, 256, 0, stream>>>(
        W_comb, b_comb, emb, token, ctx, W_hh, b_ih, b_hh, h, xvec, ghh);
    // K4: gates_ih + LSTM cell (256 MB); writes h_new/c_new to d_out
    k4_ih_cell<<<HD, 256, 0, stream>>>(W_ih, ghh, xvec, c, out);
    // K5: logits = W_out @ h_new (64 MB) + fused last-block log_softmax -> logp
    k5_out_lsm<<<HD, 256, 0, stream>>>(W_out, b_out, out + HD, logits, out, cnt5);
}

// Round 9
// 144.023 us; speedup vs baseline: 2.1955x; 2.1955x over previous
//
#include <hip/hip_runtime.h>
#include <math.h>

#define HD 4096
#define LD 2048

typedef float f32x4 __attribute__((ext_vector_type(4)));

// ---------------- reduction helpers ----------------
__device__ __forceinline__ float wave_sum(float v) {
#pragma unroll
    for (int off = 32; off > 0; off >>= 1) v += __shfl_down(v, off, 64);
    return v;
}
__device__ __forceinline__ float wave_max(float v) {
#pragma unroll
    for (int off = 32; off > 0; off >>= 1) v = fmaxf(v, __shfl_down(v, off, 64));
    return v;
}
__device__ __forceinline__ float block_sum256(float v, float* sm) {
    v = wave_sum(v);
    if ((threadIdx.x & 63) == 0) sm[threadIdx.x >> 6] = v;
    __syncthreads();
    float r = sm[0] + sm[1] + sm[2] + sm[3];
    __syncthreads();
    return r;
}
__device__ __forceinline__ float block_max256(float v, float* sm) {
    v = wave_max(v);
    if ((threadIdx.x & 63) == 0) sm[threadIdx.x >> 6] = v;
    __syncthreads();
    float r = fmaxf(fmaxf(sm[0], sm[1]), fmaxf(sm[2], sm[3]));
    __syncthreads();
    return r;
}

// ---------------- per-thread partial dots (256-thread blocks) ----------------
// W rows are read-once: non-temporal (no L2 allocate). X vectors stay cached.
__device__ __forceinline__ float pdot4096(const f32x4* __restrict__ W4,
                                          const float4* __restrict__ X4, int t) {
    float a0 = 0.f, a1 = 0.f;
#pragma unroll
    for (int i = 0; i < 4; i += 2) {
        int idx = i * 256 + t;
        f32x4 w = __builtin_nontemporal_load(W4 + idx);
        float4 x = X4[idx];
        a0 = fmaf(w[0], x.x, a0); a0 = fmaf(w[1], x.y, a0);
        a0 = fmaf(w[2], x.z, a0); a0 = fmaf(w[3], x.w, a0);
        int idx2 = idx + 256;
        f32x4 w2 = __builtin_nontemporal_load(W4 + idx2);
        float4 x2 = X4[idx2];
        a1 = fmaf(w2[0], x2.x, a1); a1 = fmaf(w2[1], x2.y, a1);
        a1 = fmaf(w2[2], x2.z, a1); a1 = fmaf(w2[3], x2.w, a1);
    }
    return a0 + a1;
}
__device__ __forceinline__ float pdot8192(const f32x4* __restrict__ W4,
                                          const float4* __restrict__ X1,
                                          const float4* __restrict__ X2, int t) {
    float a0 = 0.f, a1 = 0.f;
#pragma unroll
    for (int i = 0; i < 4; ++i) {
        int idx = i * 256 + t;
        f32x4 w = __builtin_nontemporal_load(W4 + idx);
        float4 x = X1[idx];
        a0 = fmaf(w[0], x.x, a0); a0 = fmaf(w[1], x.y, a0);
        a0 = fmaf(w[2], x.z, a0); a0 = fmaf(w[3], x.w, a0);
        int idx2 = idx + 1024;
        f32x4 w2 = __builtin_nontemporal_load(W4 + idx2);
        float4 x2 = X2[idx];
        a1 = fmaf(w2[0], x2.x, a1); a1 = fmaf(w2[1], x2.y, a1);
        a1 = fmaf(w2[2], x2.z, a1); a1 = fmaf(w2[3], x2.w, a1);
    }
    return a0 + a1;
}

// hh filler row: ghh[r] = W_hh[r]·h + b_ih[r] + b_hh[r]
__device__ __forceinline__ void hh_row(
    int r, const float* __restrict__ Whh, const float* __restrict__ bih,
    const float* __restrict__ bhh, const float* __restrict__ h,
    float* __restrict__ ghh)
{
    const int t = threadIdx.x;
    float v = pdot4096(reinterpret_cast<const f32x4*>(Whh + (size_t)r * HD),
                       reinterpret_cast<const float4*>(h), t);
    __shared__ float smr[4];
    float acc = wave_sum(v);
    if ((t & 63) == 0) smr[t >> 6] = acc;
    __syncthreads();
    if (t == 0) ghh[r] = smr[0] + smr[1] + smr[2] + smr[3] + bih[r] + bhh[r];
}

// ---------------- K1: attn logits (2048) + hh rows [0,4096) ----------------
__global__ __launch_bounds__(256) void k1_attn_hh(
    const float* __restrict__ Wattn, const float* __restrict__ battn,
    const float* __restrict__ emb, const int* __restrict__ token,
    const float* __restrict__ h,
    const float* __restrict__ Whh, const float* __restrict__ bih,
    const float* __restrict__ bhh,
    float* __restrict__ attn_logits, float* __restrict__ ghh)
{
    const int bx = blockIdx.x;
    const int t = threadIdx.x;
    if (bx < LD) {
        const float* x1 = emb + (size_t)token[0] * HD;
        float v = pdot8192(reinterpret_cast<const f32x4*>(Wattn + (size_t)bx * 8192),
                           reinterpret_cast<const float4*>(x1),
                           reinterpret_cast<const float4*>(h), t);
        __shared__ float sm[4];
        float acc = wave_sum(v);
        if ((t & 63) == 0) sm[t >> 6] = acc;
        __syncthreads();
        if (t == 0) attn_logits[bx] = sm[0] + sm[1] + sm[2] + sm[3] + battn[bx];
    } else {
        hh_row(bx - LD, Whh, bih, bhh, h, ghh);
    }
}

// ---------------- K2: softmax+ctx (64 col-blocks) + attn_w writer + hh [4096,10240) ------
__global__ __launch_bounds__(256) void k2_ctx_hh(
    const float* __restrict__ logits, const float* __restrict__ enc,
    const float* __restrict__ Whh, const float* __restrict__ bih,
    const float* __restrict__ bhh, const float* __restrict__ h,
    float* __restrict__ ctx, float* __restrict__ attn_out, float* __restrict__ ghh)
{
    const int bx = blockIdx.x;
    const int t = threadIdx.x;
    if (bx <= 64) {
        // redundant softmax per block (2048 logits from L2)
        __shared__ float sm[4];
        float vals[8];
        float m = -INFINITY;
#pragma unroll
        for (int i = 0; i < 8; ++i) { vals[i] = logits[i * 256 + t]; m = fmaxf(m, vals[i]); }
        m = block_max256(m, sm);
        float s = 0.f;
#pragma unroll
        for (int i = 0; i < 8; ++i) { vals[i] = expf(vals[i] - m); s += vals[i]; }
        s = block_sum256(s, sm);
        const float inv = 1.f / s;
        if (bx == 64) {
#pragma unroll
            for (int i = 0; i < 8; ++i) attn_out[i * 256 + t] = vals[i] * inv;
            return;
        }
        __shared__ float smw[2048];
#pragma unroll
        for (int i = 0; i < 8; ++i) smw[i * 256 + t] = vals[i] * inv;
        __syncthreads();
        // block bx covers 64 cols (16 float4): thread rg = t>>4 (128 rows each), cc = t&15
        const int rg = t >> 4;
        const int cc = t & 15;
        const int col4 = bx * 16 + cc;
        const float4* E = reinterpret_cast<const float4*>(enc);
        float4 acc = make_float4(0.f, 0.f, 0.f, 0.f);
        const int k0 = rg * 128;
#pragma unroll 8
        for (int k = k0; k < k0 + 128; ++k) {
            float wv = smw[k];
            float4 ev = E[(size_t)k * 1024 + col4];
            acc.x = fmaf(wv, ev.x, acc.x); acc.y = fmaf(wv, ev.y, acc.y);
            acc.z = fmaf(wv, ev.z, acc.z); acc.w = fmaf(wv, ev.w, acc.w);
        }
        __shared__ float4 red[16][16];
        red[rg][cc] = acc;
        __syncthreads();
        if (t < 16) {
            float4 s2 = red[0][t];
#pragma unroll
            for (int k = 1; k < 16; ++k) {
                float4 v = red[k][t];
                s2.x += v.x; s2.y += v.y; s2.z += v.z; s2.w += v.w;
            }
            reinterpret_cast<float4*>(ctx)[bx * 16 + t] = s2;
        }
    } else {
        hh_row(4096 + (bx - 65), Whh, bih, bhh, h, ghh);
    }
}

// ---------------- K3: comb (4096 rows) + hh rows [10240,16384) ----------------
__global__ __launch_bounds__(256) void k3_comb_hh(
    const float* __restrict__ W, const float* __restrict__ bias,
    const float* __restrict__ emb, const int* __restrict__ token,
    const float* __restrict__ ctx,
    const float* __restrict__ Whh, const float* __restrict__ bih,
    const float* __restrict__ bhh, const float* __restrict__ h,
    float* __restrict__ xvec, float* __restrict__ ghh)
{
    const int bx = blockIdx.x;
    const int t = threadIdx.x;
    if (bx < HD) {
        const float* x1 = emb + (size_t)token[0] * HD;
        float v = pdot8192(reinterpret_cast<const f32x4*>(W + (size_t)bx * 8192),
                           reinterpret_cast<const float4*>(x1),
                           reinterpret_cast<const float4*>(ctx), t);
        __shared__ float sm[4];
        float acc = wave_sum(v);
        if ((t & 63) == 0) sm[t >> 6] = acc;
        __syncthreads();
        if (t == 0) xvec[bx] = fmaxf(sm[0] + sm[1] + sm[2] + sm[3] + bias[bx], 0.f);
    } else {
        hh_row(10240 + (bx - HD), Whh, bih, bhh, h, ghh);
    }
}

// ---------------- K4: gates_ih (4 rows per block) + LSTM cell fused ----------------
__global__ __launch_bounds__(256) void k4_ih_cell(
    const float* __restrict__ Wih, const float* __restrict__ ghh,
    const float* __restrict__ x, const float* __restrict__ c,
    float* __restrict__ out)
{
    const int j = blockIdx.x;
    const int t = threadIdx.x;
    const float4* X = reinterpret_cast<const float4*>(x);
    float acc[4];
#pragma unroll
    for (int g = 0; g < 4; ++g)
        acc[g] = pdot4096(reinterpret_cast<const f32x4*>(Wih + (size_t)(g * HD + j) * HD), X, t);
    __shared__ float sm[4][4];
#pragma unroll
    for (int g = 0; g < 4; ++g) {
        float v = wave_sum(acc[g]);
        if ((t & 63) == 0) sm[t >> 6][g] = v;
    }
    __syncthreads();
    if (t == 0) {
        float gi = sm[0][0] + sm[1][0] + sm[2][0] + sm[3][0] + ghh[j];
        float gf = sm[0][1] + sm[1][1] + sm[2][1] + sm[3][1] + ghh[HD + j];
        float gg = sm[0][2] + sm[1][2] + sm[2][2] + sm[3][2] + ghh[2 * HD + j];
        float go = sm[0][3] + sm[1][3] + sm[2][3] + sm[3][3] + ghh[3 * HD + j];
        float si = 1.f / (1.f + expf(-gi));
        float sf = 1.f / (1.f + expf(-gf));
        float so = 1.f / (1.f + expf(-go));
        float cn = sf * c[j] + si * tanhf(gg);
        float hn = so * tanhf(cn);
        out[HD + j] = hn;       // h_new
        out[2 * HD + j] = cn;   // c_new
    }
}

// ---------------- K5: logits = W_out · h_new + b_out ----------------
__global__ __launch_bounds__(256) void k5_out(
    const float* __restrict__ W, const float* __restrict__ bias,
    const float* __restrict__ x, float* __restrict__ out)
{
    const int row = blockIdx.x;
    const int t = threadIdx.x;
    float v = pdot4096(reinterpret_cast<const f32x4*>(W + (size_t)row * HD),
                       reinterpret_cast<const float4*>(x), t);
    __shared__ float sm[4];
    float acc = wave_sum(v);
    if ((t & 63) == 0) sm[t >> 6] = acc;
    __syncthreads();
    if (t == 0) out[row] = sm[0] + sm[1] + sm[2] + sm[3] + bias[row];
}

// ---------------- K6: log_softmax over 4096 (1024 threads) ----------------
__global__ __launch_bounds__(1024) void k6_logsoftmax(
    const float* __restrict__ logits, float* __restrict__ out)
{
    __shared__ float sm[16];
    const int t = threadIdx.x;
    float vals[4];
    float m = -INFINITY;
#pragma unroll
    for (int i = 0; i < 4; ++i) { vals[i] = logits[i * 1024 + t]; m = fmaxf(m, vals[i]); }
    m = wave_max(m);
    if ((t & 63) == 0) sm[t >> 6] = m;
    __syncthreads();
    float mm = -INFINITY;
#pragma unroll
    for (int k = 0; k < 16; ++k) mm = fmaxf(mm, sm[k]);
    __syncthreads();
    float s = 0.f;
#pragma unroll
    for (int i = 0; i < 4; ++i) s += expf(vals[i] - mm);
    s = wave_sum(s);
    if ((t & 63) == 0) sm[t >> 6] = s;
    __syncthreads();
    float ss = 0.f;
#pragma unroll
    for (int k = 0; k < 16; ++k) ss += sm[k];
    float lse = mm + logf(ss);
#pragma unroll
    for (int i = 0; i < 4; ++i) out[i * 1024 + t] = vals[i] - lse;
}

extern "C" void kernel_launch(void* const* d_in, const int* in_sizes, int n_in,
                              void* d_out, int out_size, void* d_ws, size_t ws_size,
                              hipStream_t stream)
{
    const int*   token  = (const int*)  d_in[0];
    const float* h      = (const float*)d_in[1];
    const float* c      = (const float*)d_in[2];
    const float* enc    = (const float*)d_in[3];
    const float* emb    = (const float*)d_in[4];
    const float* W_attn = (const float*)d_in[5];
    const float* b_attn = (const float*)d_in[6];
    const float* W_comb = (const float*)d_in[7];
    const float* b_comb = (const float*)d_in[8];
    const float* W_ih   = (const float*)d_in[9];
    const float* W_hh   = (const float*)d_in[10];
    const float* b_ih   = (const float*)d_in[11];
    const float* b_hh   = (const float*)d_in[12];
    const float* W_out  = (const float*)d_in[13];
    const float* b_out  = (const float*)d_in[14];
    float* out = (float*)d_out;  // [logp 4096 | h_new 4096 | c_new 4096 | attn_w 2048]

    // ws layout (floats)
    float* ws          = (float*)d_ws;
    float* attn_logits = ws;               // 2048
    float* ghh         = ws + 2048;        // 16384
    float* ctx         = ws + 18432;       // 4096
    float* xvec        = ws + 22528;       // 4096
    float* logits      = ws + 26624;       // 4096

    // K1: attn logits (64 MB) + hh rows 0..4095 (64 MB)
    k1_attn_hh<<<LD + 4096, 256, 0, stream>>>(
        W_attn, b_attn, emb, token, h, W_hh, b_ih, b_hh, attn_logits, ghh);
    // K2: softmax + coalesced ctx (32 MB) + attn_w writer + hh rows 4096..10239 (96 MB)
    k2_ctx_hh<<<65 + 6144, 256, 0, stream>>>(
        attn_logits, enc, W_hh, b_ih, b_hh, h, ctx, out + 3 * HD, ghh);
    // K3: comb (128 MB) + hh rows 10240..16383 (96 MB)
    k3_comb_hh<<<HD + 6144, 256, 0, stream>>>(
        W_comb, b_comb, emb, token, ctx, W_hh, b_ih, b_hh, h, xvec, ghh);
    // K4: gates_ih + LSTM cell (256 MB); writes h_new/c_new to d_out
    k4_ih_cell<<<HD, 256, 0, stream>>>(W_ih, ghh, xvec, c, out);
    // K5: logits = W_out @ h_new (64 MB)
    k5_out<<<HD, 256, 0, stream>>>(W_out, b_out, out + HD, logits);
    // K6: log_softmax -> logp
    k6_logsoftmax<<<1, 1024, 0, stream>>>(logits, out);
}